// Round 5
// baseline (111.714 us; speedup 1.0000x reference)
//
#include <hip/hip_runtime.h>
#include <math.h>

// PCEN, single fused kernel:
//   - each thread owns a 32-step chunk of one float4 feature-lane,
//     x kept in registers (32 x float4 = 128 VGPR)
//   - block = 8 seq4 x 32 chunks = 1024-step span
//   - cross-chunk carry: truncated 8-chunk (256-step) window, a^256 ~ 1.5e-3
//     (validated round 2: absmax at the 0.0039 comparison floor)
//   - halo: every thread computes one 8-step sub-partial (balanced),
//     combined in LDS with a^8 weights; carry = 8-term Horner with a^32
//   - chunk-0 exact init M[0]=x[0] folded in branch-free:
//       partial += a^32 * x0 ; produce j=0: m += a * x0
//
// M[t] = a*M[t-1] + s*x[t];  out = sqrt(x*(M+eps)^-0.98 + 2) - sqrt(2)

#define B_     64
#define T_     8192
#define F4_    20                 // 80 f32 = 20 float4
#define NSEQ4  (B_ * F4_)         // 1280 float4 lanes
#define LCH_   32                 // timesteps per thread
#define SPB_   8                  // seq4 per block
#define CPB_   32                 // chunks per block (256 threads)
#define SPAN_  (LCH_ * CPB_)      // 1024 steps per block
#define TB_    (T_ / SPAN_)       // 8 time-blocks
#define NG_    (NSEQ4 / SPB_)     // 160 seq groups
#define H_     8                  // carry horizon in chunks (256 steps)
#define SA_    0.025f
#define AA_    0.975f
#define A8_    0.81665176f        // 0.975^8
#define A32_   0.44478250f        // 0.975^32

__device__ __forceinline__ float pcen1(float xv, float m) {
    float g = exp2f(-0.98f * log2f(m + 1e-6f));   // (m+eps)^(-alpha)
    return sqrtf(fmaf(xv, g, 2.0f)) - 1.4142135623730951f;
}

__device__ __forceinline__ float4 pcen4(float4 xv, float4 m) {
    float4 o;
    o.x = pcen1(xv.x, m.x);
    o.y = pcen1(xv.y, m.y);
    o.z = pcen1(xv.z, m.z);
    o.w = pcen1(xv.w, m.w);
    return o;
}

__device__ __forceinline__ void ema4(float4& m, const float4 xv) {
    m.x = fmaf(AA_, m.x, SA_ * xv.x);
    m.y = fmaf(AA_, m.y, SA_ * xv.y);
    m.z = fmaf(AA_, m.z, SA_ * xv.z);
    m.w = fmaf(AA_, m.w, SA_ * xv.w);
}

__device__ __forceinline__ void fma4s(float4& d, float c, const float4 v) {
    d.x = fmaf(c, v.x, d.x);
    d.y = fmaf(c, v.y, d.y);
    d.z = fmaf(c, v.z, d.z);
    d.w = fmaf(c, v.w, d.w);
}

__global__ void __launch_bounds__(256, 2)
pcen_fused(const float4* __restrict__ x4, float4* __restrict__ o4) {
    __shared__ float4 PP[H_ + CPB_][SPB_];   // rows 0..7 halo, 8..39 local partials
    __shared__ float4 HS[H_][4][SPB_];       // halo 8-step sub-partials

    const int tid = threadIdx.x;
    const int s   = tid & (SPB_ - 1);        // seq4 within block
    const int lc  = tid >> 3;                // local chunk 0..31

    const int g   = blockIdx.x % NG_;
    const int tb  = blockIdx.x / NG_;

    const int r   = g * SPB_ + s;            // global float4-lane id
    const int b   = r / F4_;
    const int f4  = r - b * F4_;

    const size_t  seqbase = (size_t)b * ((size_t)T_ * F4_) + f4;
    const int     t0      = tb * SPAN_ + lc * LCH_;
    const float4* xp      = x4 + seqbase + (size_t)t0 * F4_;
    float4*       op      = o4 + seqbase + (size_t)t0 * F4_;

    // ---- own-chunk loads into registers ----
    float4 xv[LCH_];
    #pragma unroll
    for (int j = 0; j < LCH_; ++j) xv[j] = xp[(size_t)j * F4_];

    // ---- halo sub-partial: one 8-step zero-init EMA per thread ----
    float4 hsub = make_float4(0.f, 0.f, 0.f, 0.f);
    if (tb > 0) {                            // block-uniform branch
        const int hc = lc >> 2;
        const int q  = lc & 3;
        const int th = tb * SPAN_ - H_ * LCH_ + hc * LCH_ + q * 8;
        const float4* hp = x4 + seqbase + (size_t)th * F4_;
        #pragma unroll
        for (int i = 0; i < 8; ++i) ema4(hsub, hp[(size_t)i * F4_]);
    }
    HS[lc >> 2][lc & 3][s] = hsub;

    // ---- own zero-init partial (+ exact fix for global chunk 0) ----
    float4 pm = make_float4(0.f, 0.f, 0.f, 0.f);
    #pragma unroll
    for (int j = 0; j < LCH_; ++j) ema4(pm, xv[j]);
    const float c0 = (tb == 0 && lc == 0) ? A32_ : 0.0f;
    fma4s(pm, c0, xv[0]);                    // exact chunk-0 partial
    PP[H_ + lc][s] = pm;

    __syncthreads();

    // ---- combine halo subs into PP rows 0..7 ----
    if (tid < H_ * SPB_) {
        const int sc = tid & (SPB_ - 1);
        const int hc = tid >> 3;
        float4 e = HS[hc][0][sc];
        #pragma unroll
        for (int q = 1; q < 4; ++q) {
            float4 t = HS[hc][q][sc];
            e.x = fmaf(A8_, e.x, t.x);
            e.y = fmaf(A8_, e.y, t.y);
            e.z = fmaf(A8_, e.z, t.z);
            e.w = fmaf(A8_, e.w, t.w);
        }
        PP[hc][sc] = e;
    }

    __syncthreads();

    // ---- carry: 8-term Horner over window rows lc .. lc+7 ----
    float4 m = PP[lc][s];
    #pragma unroll
    for (int k = 1; k < H_; ++k) {
        float4 t = PP[lc + k][s];
        m.x = fmaf(A32_, m.x, t.x);
        m.y = fmaf(A32_, m.y, t.y);
        m.z = fmaf(A32_, m.z, t.z);
        m.w = fmaf(A32_, m.w, t.w);
    }

    // ---- produce: EMA + pcen from register x, 32 stores ----
    const float fix = (tb == 0 && lc == 0) ? AA_ : 0.0f;
    ema4(m, xv[0]);
    fma4s(m, fix, xv[0]);                    // chunk 0: m = x[0] exactly
    op[0] = pcen4(xv[0], m);
    #pragma unroll
    for (int j = 1; j < LCH_; ++j) {
        ema4(m, xv[j]);
        op[(size_t)j * F4_] = pcen4(xv[j], m);
    }
}

extern "C" void kernel_launch(void* const* d_in, const int* in_sizes, int n_in,
                              void* d_out, int out_size, void* d_ws, size_t ws_size,
                              hipStream_t stream) {
    const float4* x4 = (const float4*)d_in[0];
    float4*       o4 = (float4*)d_out;

    pcen_fused<<<dim3(NG_ * TB_), dim3(256), 0, stream>>>(x4, o4);
}

// Round 6
// 93.831 us; speedup vs baseline: 1.1906x; 1.1906x over previous
//
#include <hip/hip_runtime.h>
#include <math.h>

// PCEN, single fused kernel, v2 (occupancy + coalescing fix):
//   - thread owns a 16-step chunk of one float4 lane (xv[16] = 64 VGPR)
//   - block = 16 seq4 x 16 chunks = 256-step span; grid tb-major so the
//     whole GPU walks time together (halo stripe stays L3-resident)
//   - halo = previous block's span (256 steps): each thread computes the
//     u-space zero-init partial of its own chunk shifted back one span
//   - carry = 16-term Horner over [halo partials | own partials] in LDS,
//     weight a^16 = 0.66692; truncation a^256 ~ 1.5e-3 (validated floor)
//   - u-space accumulation (u = a*u + x; m = s*u) -> 1 fma/comp/step,
//     two independent 8-chains per 16-step partial
//   - nontemporal output stores (never re-read -> don't evict x from L3)
//
// M[t] = a*M[t-1] + s*x[t], M[0]=x[0]
// out  = sqrt(x*(M+eps)^-0.98 + 2) - sqrt(2)

#define B_     64
#define T_     8192
#define F4_    20                 // 80 f32 = 20 float4
#define NSEQ4  (B_ * F4_)         // 1280 float4 lanes
#define LCH_   16                 // timesteps per thread
#define SPB_   16                 // seq4 per block
#define CPB_   16                 // chunks per block (256 threads)
#define SPAN_  (LCH_ * CPB_)      // 256 steps per block
#define TB_    (T_ / SPAN_)       // 32 time-blocks
#define NG_    (NSEQ4 / SPB_)     // 80 seq groups
#define SA_    0.025f
#define AA_    0.975f
#define A8_    0.81665182f        // 0.975^8
#define A16_   0.66692016f        // 0.975^16
#define A16S_  26.676807f         // A16_ / SA_  (chunk-0 exact fix, u-space)

typedef float f4v __attribute__((ext_vector_type(4)));

__device__ __forceinline__ float pcen1(float xv, float m) {
    float g = exp2f(-0.98f * log2f(m + 1e-6f));   // (m+eps)^(-alpha)
    return sqrtf(fmaf(xv, g, 2.0f)) - 1.4142135623730951f;
}

__device__ __forceinline__ f4v pcen4(float4 xv, float4 m) {
    f4v o;
    o.x = pcen1(xv.x, m.x);
    o.y = pcen1(xv.y, m.y);
    o.z = pcen1(xv.z, m.z);
    o.w = pcen1(xv.w, m.w);
    return o;
}

// d = c*d + v   (u-space EMA step / Horner step)
__device__ __forceinline__ void hstep(float4& d, float c, const float4 v) {
    d.x = fmaf(c, d.x, v.x);
    d.y = fmaf(c, d.y, v.y);
    d.z = fmaf(c, d.z, v.z);
    d.w = fmaf(c, d.w, v.w);
}

// d += c*v
__device__ __forceinline__ void faxpy(float4& d, float c, const float4 v) {
    d.x = fmaf(c, v.x, d.x);
    d.y = fmaf(c, v.y, d.y);
    d.z = fmaf(c, v.z, d.z);
    d.w = fmaf(c, v.w, d.w);
}

// m = a*m + s*x   (m-space EMA, produce phase)
__device__ __forceinline__ void ema4(float4& m, const float4 xv) {
    m.x = fmaf(AA_, m.x, SA_ * xv.x);
    m.y = fmaf(AA_, m.y, SA_ * xv.y);
    m.z = fmaf(AA_, m.z, SA_ * xv.z);
    m.w = fmaf(AA_, m.w, SA_ * xv.w);
}

__global__ void __launch_bounds__(256, 4)
pcen_fused(const float4* __restrict__ x4, float4* __restrict__ o4) {
    __shared__ float4 P[2 * CPB_][SPB_];   // rows 0..15 halo, 16..31 own (u-space)

    const int tid = threadIdx.x;
    const int s   = tid & (SPB_ - 1);      // seq4 within block (lane-low bits)
    const int lc  = tid >> 4;              // local chunk 0..15

    const int g   = blockIdx.x % NG_;      // tb-major: time stripes run together
    const int tb  = blockIdx.x / NG_;

    const int r   = g * SPB_ + s;          // global float4-lane id
    const int b   = r / F4_;
    const int f4  = r - b * F4_;

    const size_t  seqbase = (size_t)b * ((size_t)T_ * F4_) + f4;
    const int     t0      = tb * SPAN_ + lc * LCH_;
    const float4* xp      = x4 + seqbase + (size_t)t0 * F4_;
    float4*       op      = o4 + seqbase + (size_t)t0 * F4_;

    // ---- own chunk -> registers (16 x float4 = 64 VGPR) ----
    float4 xv[LCH_];
    #pragma unroll
    for (int j = 0; j < LCH_; ++j) xv[j] = xp[(size_t)j * F4_];

    // ---- halo partial: own chunk shifted back one span, u-space ----
    float4 hu = make_float4(0.f, 0.f, 0.f, 0.f);
    if (tb > 0) {                          // block-uniform branch
        const float4* hp = xp - (size_t)SPAN_ * F4_;
        float4 u0 = make_float4(0.f, 0.f, 0.f, 0.f);
        float4 u1 = make_float4(0.f, 0.f, 0.f, 0.f);
        #pragma unroll
        for (int j = 0; j < 8; ++j) {      // two independent 8-chains
            hstep(u0, AA_, hp[(size_t)j * F4_]);
            hstep(u1, AA_, hp[(size_t)(j + 8) * F4_]);
        }
        hu = u1;
        faxpy(hu, A8_, u0);                // hu = a^8*u0 + u1
    }
    P[lc][s] = hu;

    // ---- own zero-init partial (u-space, two 8-chains) ----
    {
        float4 u0 = make_float4(0.f, 0.f, 0.f, 0.f);
        float4 u1 = make_float4(0.f, 0.f, 0.f, 0.f);
        #pragma unroll
        for (int j = 0; j < 8; ++j) {
            hstep(u0, AA_, xv[j]);
            hstep(u1, AA_, xv[j + 8]);
        }
        float4 pu = u1;
        faxpy(pu, A8_, u0);
        const float c0 = (tb == 0 && lc == 0) ? A16S_ : 0.0f;
        faxpy(pu, c0, xv[0]);              // exact M[0]=x[0] fix (u-space)
        P[CPB_ + lc][s] = pu;
    }

    __syncthreads();

    // ---- carry: 16-term Horner over rows lc .. lc+15 (oldest -> newest) ----
    float4 u = P[lc][s];
    #pragma unroll
    for (int k = 1; k < CPB_; ++k) hstep(u, A16_, P[lc + k][s]);

    float4 m;                              // m = s*u
    m.x = SA_ * u.x; m.y = SA_ * u.y; m.z = SA_ * u.z; m.w = SA_ * u.w;

    // ---- produce: EMA + pcen from register x, nontemporal stores ----
    const float fix = (tb == 0 && lc == 0) ? AA_ : 0.0f;
    ema4(m, xv[0]);
    faxpy(m, fix, xv[0]);                  // global t=0: m = x[0] exactly
    __builtin_nontemporal_store(pcen4(xv[0], m), (f4v*)op);
    #pragma unroll
    for (int j = 1; j < LCH_; ++j) {
        ema4(m, xv[j]);
        __builtin_nontemporal_store(pcen4(xv[j], m), (f4v*)(op + (size_t)j * F4_));
    }
}

extern "C" void kernel_launch(void* const* d_in, const int* in_sizes, int n_in,
                              void* d_out, int out_size, void* d_ws, size_t ws_size,
                              hipStream_t stream) {
    const float4* x4 = (const float4*)d_in[0];
    float4*       o4 = (float4*)d_out;

    pcen_fused<<<dim3(NG_ * TB_), dim3(256), 0, stream>>>(x4, o4);
}